// Round 8
// baseline (89.833 us; speedup 1.0000x reference)
//
#include <hip/hip_runtime.h>
#include <stdint.h>

#define FEAT 1024
#define BATCH 4096
#define SM (FEAT * FEAT)

typedef float f32x4 __attribute__((ext_vector_type(4)));
typedef short bf16x8 __attribute__((ext_vector_type(8)));
typedef unsigned short u16x8 __attribute__((ext_vector_type(8)));
typedef unsigned short u16x4 __attribute__((ext_vector_type(4)));

__device__ inline unsigned short f32_to_bf16(float f) {
  union { float f; uint32_t u; } v; v.f = f;
  uint32_t u = v.u;
  uint32_t lsb = (u >> 16) & 1u;
  u += 0x7fffu + lsb;  // RNE
  return (unsigned short)(u >> 16);
}

__device__ inline float bf16_to_f32(unsigned short h) {
  union { uint32_t u; float f; } v; v.u = (uint32_t)h << 16; return v.f;
}

__device__ inline void gload_lds16(const void* g, void* l) {
  __builtin_amdgcn_global_load_lds(
      (__attribute__((address_space(1))) void*)(g),
      (__attribute__((address_space(3))) void*)(l),
      16, 0, 0);
}

// ---- fused prep: Dr[j]=bf16(c_j*M_j) (all j), Dt[j>>1]=transposed (odd j only),
// ---- Xb=bf16(features), Wb=bf16(proj_w). 2304 blocks.
__global__ void conv_all(const float* __restrict__ M, const float* __restrict__ feat,
                         const float* __restrict__ pw, const float* __restrict__ mean,
                         const float* __restrict__ eps, const float* __restrict__ logvar,
                         unsigned short* __restrict__ Dr, unsigned short* __restrict__ Dt,
                         unsigned short* __restrict__ Xb, unsigned short* __restrict__ Wb) {
  const int bid = blockIdx.x;
  const int t = threadIdx.x;
  if (bid < 2048) {
    __shared__ unsigned short Ts[64][68];
    const int j = bid >> 8, rem = bid & 255;
    const int n0 = (rem >> 4) * 64, k0 = (rem & 15) * 64;
    float lv = fminf(fmaxf(logvar[j], -8.f), 2.f);
    const float c = mean[j] + eps[j] * expf(0.5f * lv);
    const float* src = M + (size_t)j * SM;
    unsigned short* dr = Dr + (size_t)j * SM;
#pragma unroll
    for (int i2 = 0; i2 < 4; ++i2) {
      int fidx = i2 * 256 + t;
      int kl = fidx >> 4, nf = fidx & 15;
      float4 v = *(const float4*)(src + (size_t)(k0 + kl) * FEAT + n0 + nf * 4);
      u16x4 o;
      o[0] = f32_to_bf16(c * v.x); o[1] = f32_to_bf16(c * v.y);
      o[2] = f32_to_bf16(c * v.z); o[3] = f32_to_bf16(c * v.w);
      *(u16x4*)&Ts[kl][nf * 4] = o;
      *(u16x4*)(dr + (size_t)(k0 + kl) * FEAT + n0 + nf * 4) = o;
    }
    __syncthreads();
    if (j & 1) {
      unsigned short* dt = Dt + (size_t)(j >> 1) * SM;
#pragma unroll
      for (int i2 = 0; i2 < 2; ++i2) {
        int cidx = t * 2 + i2;
        int nl = cidx >> 3, kc = (cidx & 7) * 8;
        u16x8 o;
#pragma unroll
        for (int r = 0; r < 8; ++r) o[r] = Ts[kc + r][nl];
        *(u16x8*)(dt + (size_t)(n0 + nl) * FEAT + k0 + kc) = o;
      }
    }
  } else {
    for (int i = (bid - 2048) * 256 + t; i < 655360; i += 65536) {
      const float* in; unsigned short* o8; int ci;
      if (i < 524288) { in = feat; o8 = Xb; ci = i; }
      else            { in = pw;   o8 = Wb; ci = i - 524288; }
      const float4* p = (const float4*)in + (size_t)ci * 2;
      float4 a = p[0], b = p[1];
      u16x8 o;
      o[0] = f32_to_bf16(a.x); o[1] = f32_to_bf16(a.y);
      o[2] = f32_to_bf16(a.z); o[3] = f32_to_bf16(a.w);
      o[4] = f32_to_bf16(b.x); o[5] = f32_to_bf16(b.y);
      o[6] = f32_to_bf16(b.z); o[7] = f32_to_bf16(b.w);
      *((u16x8*)o8 + ci) = o;
    }
  }
}

// ---- 2-phase double-buffered 128x128-tile GEMM core (16 K-steps of 64) ----
// 4 waves (2x2), wave-tile 64x64, acc[4][4]. LDS 64 KB: As 2x8192, Bs 2x8192.
// XOR-swizzled (colbyte ^= (row&7)<<4), pre-swizzled global source.
__device__ __forceinline__ void gemm_core128(
    const unsigned short* __restrict__ Ap, const unsigned short* __restrict__ Btp,
    int arow0, int bcol0, int t,
    unsigned short* As, unsigned short* Bs, f32x4 (&acc)[4][4]) {
  const int lane = t & 63;
  const int wid = t >> 6, wm = wid >> 1, wn = wid & 1;
  const int ar = t >> 3;
  const int acb = (((t & 7) ^ ((t >> 3) & 7)) << 4);
  const unsigned short* Abase = Ap + (size_t)(arow0 + ar) * FEAT + (acb >> 1);
  const unsigned short* Bbase = Btp + (size_t)(bcol0 + ar) * FEAT + (acb >> 1);
  unsigned short* AsP = As + t * 8;
  unsigned short* BsP = Bs + t * 8;

#pragma unroll
  for (int p = 0; p < 4; ++p) gload_lds16(Abase + (size_t)(p * 32) * FEAT, AsP + p * 2048);
#pragma unroll
  for (int p = 0; p < 4; ++p) gload_lds16(Bbase + (size_t)(p * 32) * FEAT, BsP + p * 2048);
  __syncthreads();

  for (int kt = 0; kt < 16; ++kt) {
    const int cur = kt & 1, nx = cur ^ 1;
    if (kt < 15) {
      const int ko = (kt + 1) * 64;
#pragma unroll
      for (int p = 0; p < 4; ++p)
        gload_lds16(Abase + (size_t)(p * 32) * FEAT + ko, AsP + nx * 8192 + p * 2048);
#pragma unroll
      for (int p = 0; p < 4; ++p)
        gload_lds16(Bbase + (size_t)(p * 32) * FEAT + ko, BsP + nx * 8192 + p * 2048);
    }
    const char* Asc = (const char*)(As + cur * 8192);
    const char* Bsc = (const char*)(Bs + cur * 8192);
#pragma unroll
    for (int kk = 0; kk < 2; ++kk) {
      bf16x8 a[4], b[4];
      const int cbase = kk * 64 + ((lane >> 4) << 4);
#pragma unroll
      for (int m = 0; m < 4; ++m) {
        int r = wm * 64 + m * 16 + (lane & 15);
        a[m] = *(const bf16x8*)(Asc + r * 128 + (cbase ^ ((r & 7) << 4)));
      }
#pragma unroll
      for (int n = 0; n < 4; ++n) {
        int r = wn * 64 + n * 16 + (lane & 15);
        b[n] = *(const bf16x8*)(Bsc + r * 128 + (cbase ^ ((r & 7) << 4)));
      }
#pragma unroll
      for (int m = 0; m < 4; ++m)
#pragma unroll
        for (int n = 0; n < 4; ++n)
          acc[m][n] = __builtin_amdgcn_mfma_f32_16x16x32_bf16(a[m], b[n], acc[m][n], 0, 0, 0);
    }
    __syncthreads();
  }
}

// MODE 0 (L1, 256 blk): z=swz>>6; P1[z] = D2z + D2z+1 + D2z@D2z+1 -> O1+z*SM rows,
//        O2+(z>>1)*SM transposed if z odd.  lin = Dr.
// MODE 1 (L5, 256 blk): outf = A @ Bt^T (f32).
template <int MODE>
__global__ __launch_bounds__(256, 2) void gemm128(
    const unsigned short* __restrict__ A, const unsigned short* __restrict__ Bt,
    const unsigned short* __restrict__ lin,
    unsigned short* __restrict__ O1, unsigned short* __restrict__ O2,
    float* __restrict__ outf) {
  __shared__ __align__(16) unsigned short ldsbuf[32768];  // 64 KB
  unsigned short* As = ldsbuf;
  unsigned short* Bs = ldsbuf + 16384;

  const int t = threadIdx.x;
  const int lane = t & 63, wid = t >> 6, wm = wid >> 1, wn = wid & 1;
  const int swz = (blockIdx.x & 7) * 32 + (blockIdx.x >> 3);  // 256 blocks, XCD-bijective

  int bm, bn, z = 0;
  const unsigned short *Ap, *Btp;
  if (MODE == 0) {
    z = swz >> 6;                  // 4 slices x 64 tiles
    const int rem = swz & 63;
    bm = rem >> 3; bn = rem & 7;   // 8x8 tiles of 128x128
    Ap = A + (size_t)(2 * z) * SM;
    Btp = Bt + (size_t)z * SM;
  } else {
    bm = swz >> 3; bn = swz & 7;   // 32x8 tiles
    Ap = A; Btp = Bt;
  }

  f32x4 acc[4][4];
#pragma unroll
  for (int m = 0; m < 4; ++m)
#pragma unroll
    for (int n = 0; n < 4; ++n) acc[m][n] = (f32x4)0.f;

  gemm_core128(Ap, Btp, bm * 128, bn * 128, t, As, Bs, acc);

  // epilogue. C/D layout: col = lane&15, row = (lane>>4)*4 + reg [HW-verified]
#pragma unroll
  for (int m = 0; m < 4; ++m) {
    int Rb = bm * 128 + wm * 64 + m * 16 + ((lane >> 4) << 2);
#pragma unroll
    for (int n = 0; n < 4; ++n) {
      int C = bn * 128 + wn * 64 + n * 16 + (lane & 15);
      if (MODE == 0) {
        const unsigned short* aA = lin + (size_t)(2 * z) * SM;
        const unsigned short* aB = lin + (size_t)(2 * z + 1) * SM;
        unsigned short* pr = O1 + (size_t)z * SM;
        u16x4 tp;
#pragma unroll
        for (int r2 = 0; r2 < 4; ++r2) {
          size_t idx = (size_t)(Rb + r2) * FEAT + C;
          float v = acc[m][n][r2] + bf16_to_f32(aA[idx]) + bf16_to_f32(aB[idx]);
          unsigned short h = f32_to_bf16(v);
          pr[idx] = h; tp[r2] = h;
        }
        if (z & 1)
          *(u16x4*)(O2 + (size_t)(z >> 1) * SM + (size_t)C * FEAT + Rb) = tp;
      } else {
#pragma unroll
        for (int r2 = 0; r2 < 4; ++r2)
          outf[(size_t)(Rb + r2) * FEAT + C] = acc[m][n][r2];
      }
    }
  }
}

// ---- 64x64-tile full-K GEMM, 32 KB LDS, fused linear epilogue ----
// MODE 0 (L2, 512 blocks): z=swz>>8; P2[z] = P1_2z + P1_2z+1 + P1_2z@P1_2z+1
// MODE 1 (U/S, 256 blocks): O^T[C][k] = bf16( (A@Bt^T)[k][C] + lin[C][k] )
template <int MODE>
__global__ __launch_bounds__(256, 2) void gemm64(
    const unsigned short* __restrict__ A, const unsigned short* __restrict__ Bt,
    const unsigned short* __restrict__ lin, unsigned short* __restrict__ O) {
  __shared__ __align__(16) unsigned short ldsbuf[16384];  // 32 KB: As 2x4096, Bs 2x4096
  unsigned short* As = ldsbuf;
  unsigned short* Bs = ldsbuf + 8192;

  const int t = threadIdx.x;
  const int lane = t & 63, wid = t >> 6, wm = wid >> 1, wn = wid & 1;
  const int nb = (int)gridDim.x;
  const int swz = (blockIdx.x & 7) * (nb >> 3) + (blockIdx.x >> 3);  // XCD-bijective

  int bm, bn, z = 0;
  const unsigned short *Ap, *Btp;
  if (MODE == 0) {
    z = swz >> 8;
    const int tile = swz & 255;
    bm = tile >> 4; bn = tile & 15;
    Ap = A + (size_t)(2 * z) * SM;
    Btp = Bt + (size_t)z * SM;
  } else {
    bm = swz >> 4; bn = swz & 15;
    Ap = A; Btp = Bt;
  }
  const int arow0 = bm * 64, bcol0 = bn * 64;

  f32x4 acc[2][2];
#pragma unroll
  for (int m = 0; m < 2; ++m)
#pragma unroll
    for (int n = 0; n < 2; ++n) acc[m][n] = (f32x4)0.f;

  const int ar = t >> 3;
  const int acb = (((t & 7) ^ ((t >> 3) & 7)) << 4);
  const unsigned short* Abase = Ap + (size_t)(arow0 + ar) * FEAT + (acb >> 1);
  const unsigned short* Bbase = Btp + (size_t)(bcol0 + ar) * FEAT + (acb >> 1);
  unsigned short* AsP = As + t * 8;
  unsigned short* BsP = Bs + t * 8;

#pragma unroll
  for (int p = 0; p < 2; ++p) gload_lds16(Abase + (size_t)(p * 32) * FEAT, AsP + p * 2048);
#pragma unroll
  for (int p = 0; p < 2; ++p) gload_lds16(Bbase + (size_t)(p * 32) * FEAT, BsP + p * 2048);
  __syncthreads();

  for (int kt = 0; kt < 16; ++kt) {
    const int cur = kt & 1, nx = cur ^ 1;
    if (kt < 15) {
      const int ko = (kt + 1) * 64;
#pragma unroll
      for (int p = 0; p < 2; ++p)
        gload_lds16(Abase + (size_t)(p * 32) * FEAT + ko, AsP + nx * 4096 + p * 2048);
#pragma unroll
      for (int p = 0; p < 2; ++p)
        gload_lds16(Bbase + (size_t)(p * 32) * FEAT + ko, BsP + nx * 4096 + p * 2048);
    }
    const char* Asc = (const char*)(As + cur * 4096);
    const char* Bsc = (const char*)(Bs + cur * 4096);
#pragma unroll
    for (int kk = 0; kk < 2; ++kk) {
      bf16x8 a[2], b[2];
      const int cbase = kk * 64 + ((lane >> 4) << 4);
#pragma unroll
      for (int m = 0; m < 2; ++m) {
        int r = wm * 32 + m * 16 + (lane & 15);
        a[m] = *(const bf16x8*)(Asc + r * 128 + (cbase ^ ((r & 7) << 4)));
      }
#pragma unroll
      for (int n = 0; n < 2; ++n) {
        int r = wn * 32 + n * 16 + (lane & 15);
        b[n] = *(const bf16x8*)(Bsc + r * 128 + (cbase ^ ((r & 7) << 4)));
      }
#pragma unroll
      for (int m = 0; m < 2; ++m)
#pragma unroll
        for (int n = 0; n < 2; ++n)
          acc[m][n] = __builtin_amdgcn_mfma_f32_16x16x32_bf16(a[m], b[n], acc[m][n], 0, 0, 0);
    }
    __syncthreads();
  }

  // epilogue
#pragma unroll
  for (int m = 0; m < 2; ++m) {
    int Rb = arow0 + wm * 32 + m * 16 + ((lane >> 4) << 2);
#pragma unroll
    for (int n = 0; n < 2; ++n) {
      int C = bcol0 + wn * 32 + n * 16 + (lane & 15);
      if (MODE == 0) {
        const unsigned short* aA = lin + (size_t)(2 * z) * SM;
        const unsigned short* aB = lin + (size_t)(2 * z + 1) * SM;
        unsigned short* po = O + (size_t)z * SM;
#pragma unroll
        for (int r2 = 0; r2 < 4; ++r2) {
          size_t idx = (size_t)(Rb + r2) * FEAT + C;
          float v = acc[m][n][r2] + bf16_to_f32(aA[idx]) + bf16_to_f32(aB[idx]);
          po[idx] = f32_to_bf16(v);
        }
      } else {
        u16x4 lv = *(const u16x4*)(lin + (size_t)C * FEAT + Rb);
        u16x4 o;
#pragma unroll
        for (int r2 = 0; r2 < 4; ++r2)
          o[r2] = f32_to_bf16(acc[m][n][r2] + bf16_to_f32(lv[r2]));
        *(u16x4*)(O + (size_t)C * FEAT + Rb) = o;  // transposed write
      }
    }
  }
}

extern "C" void kernel_launch(void* const* d_in, const int* in_sizes, int n_in,
                              void* d_out, int out_size, void* d_ws, size_t ws_size,
                              hipStream_t stream) {
  const float* features = (const float*)d_in[0];
  const float* eps      = (const float*)d_in[1];
  const float* mean     = (const float*)d_in[2];
  const float* logvar   = (const float*)d_in[3];
  const float* task_mats= (const float*)d_in[4];
  const float* proj_w   = (const float*)d_in[5];
  float* out = (float*)d_out;

  // workspace layout (peak 54 MB):
  uint8_t* ws = (uint8_t*)d_ws;
  unsigned short* Dr  = (unsigned short*)(ws);                      //  0..16M
  unsigned short* Dt  = (unsigned short*)(ws + ((size_t)16 << 20)); // 16..24M (odd-packed)
  unsigned short* Xb  = (unsigned short*)(ws + ((size_t)24 << 20)); // 24..32M
  unsigned short* Wb  = (unsigned short*)(ws + ((size_t)32 << 20)); // 32..34M
  unsigned short* P1r = (unsigned short*)(ws + ((size_t)34 << 20)); // 34..42M (4 slices)
  unsigned short* P1t = (unsigned short*)(ws + ((size_t)42 << 20)); // 42..46M (odd-packed)
  unsigned short* P2r = (unsigned short*)(ws + ((size_t)46 << 20)); // 46..50M (DL, DR rows)
  unsigned short* Ut  = (unsigned short*)(ws + ((size_t)50 << 20)); // 50..52M ((I+DR)W^T, transposed)
  unsigned short* St  = (unsigned short*)(ws + ((size_t)52 << 20)); // 52..54M (S, transposed)

  // prep: deltas + bf16 converts
  conv_all<<<2304, 256, 0, stream>>>(task_mats, features, proj_w, mean, eps, logvar,
                                     Dr, Dt, Xb, Wb);
  // L1: P1[z] = D2z + D2z+1 + D2z@D2z+1  (4 slices, 128x128 tiles, 256 blocks)
  gemm128<0><<<256, 256, 0, stream>>>(Dr, Dt, Dr, P1r, P1t, nullptr);
  // L2: P2[z] = P1_2z + P1_2z+1 + P1_2z@P1_2z+1  (2 slices, 64x64 tiles)
  gemm64<0><<<512, 256, 0, stream>>>(P1r, P1t, P1r, P2r);
  // U = W^T + DR@W^T, written transposed: Ut[C][k]
  gemm64<1><<<256, 256, 0, stream>>>(P2r + SM, Wb, Wb, Ut);
  // S = U + DL@U, written transposed: St[C][k]
  gemm64<1><<<256, 256, 0, stream>>>(P2r, Ut, Ut, St);
  // L5: out = x @ S (f32, 128x128 tiles, 256 blocks)
  gemm128<1><<<256, 256, 0, stream>>>(Xb, St, nullptr, nullptr, nullptr, out);
}

// Round 9
// 70.154 us; speedup vs baseline: 1.2805x; 1.2805x over previous
//
#include <hip/hip_runtime.h>
#include <stdint.h>

#define FEAT 1024
#define BATCH 4096
#define SM (FEAT * FEAT)

typedef float f32x4 __attribute__((ext_vector_type(4)));
typedef short bf16x8 __attribute__((ext_vector_type(8)));
typedef unsigned short u16x8 __attribute__((ext_vector_type(8)));
typedef unsigned short u16x4 __attribute__((ext_vector_type(4)));

__device__ inline unsigned short f32_to_bf16(float f) {
  union { float f; uint32_t u; } v; v.f = f;
  uint32_t u = v.u;
  uint32_t lsb = (u >> 16) & 1u;
  u += 0x7fffu + lsb;  // RNE
  return (unsigned short)(u >> 16);
}

__device__ inline float bf16_to_f32(unsigned short h) {
  union { uint32_t u; float f; } v; v.u = (uint32_t)h << 16; return v.f;
}

__device__ inline void gload_lds16(const void* g, void* l) {
  __builtin_amdgcn_global_load_lds(
      (__attribute__((address_space(1))) void*)(g),
      (__attribute__((address_space(3))) void*)(l),
      16, 0, 0);
}

// ---- fused prep: Dr[j]=bf16(c_j*M_j) (all j), Dt[j>>1]=transposed (odd j only),
// ---- Xb=bf16(features), Wb=bf16(proj_w). 2304 blocks.
__global__ void conv_all(const float* __restrict__ M, const float* __restrict__ feat,
                         const float* __restrict__ pw, const float* __restrict__ mean,
                         const float* __restrict__ eps, const float* __restrict__ logvar,
                         unsigned short* __restrict__ Dr, unsigned short* __restrict__ Dt,
                         unsigned short* __restrict__ Xb, unsigned short* __restrict__ Wb) {
  const int bid = blockIdx.x;
  const int t = threadIdx.x;
  if (bid < 2048) {
    __shared__ unsigned short Ts[64][68];
    const int j = bid >> 8, rem = bid & 255;
    const int n0 = (rem >> 4) * 64, k0 = (rem & 15) * 64;
    float lv = fminf(fmaxf(logvar[j], -8.f), 2.f);
    const float c = mean[j] + eps[j] * expf(0.5f * lv);
    const float* src = M + (size_t)j * SM;
    unsigned short* dr = Dr + (size_t)j * SM;
#pragma unroll
    for (int i2 = 0; i2 < 4; ++i2) {
      int fidx = i2 * 256 + t;
      int kl = fidx >> 4, nf = fidx & 15;
      float4 v = *(const float4*)(src + (size_t)(k0 + kl) * FEAT + n0 + nf * 4);
      u16x4 o;
      o[0] = f32_to_bf16(c * v.x); o[1] = f32_to_bf16(c * v.y);
      o[2] = f32_to_bf16(c * v.z); o[3] = f32_to_bf16(c * v.w);
      *(u16x4*)&Ts[kl][nf * 4] = o;
      *(u16x4*)(dr + (size_t)(k0 + kl) * FEAT + n0 + nf * 4) = o;
    }
    __syncthreads();
    if (j & 1) {
      unsigned short* dt = Dt + (size_t)(j >> 1) * SM;
#pragma unroll
      for (int i2 = 0; i2 < 2; ++i2) {
        int cidx = t * 2 + i2;
        int nl = cidx >> 3, kc = (cidx & 7) * 8;
        u16x8 o;
#pragma unroll
        for (int r = 0; r < 8; ++r) o[r] = Ts[kc + r][nl];
        *(u16x8*)(dt + (size_t)(n0 + nl) * FEAT + k0 + kc) = o;
      }
    }
  } else {
    for (int i = (bid - 2048) * 256 + t; i < 655360; i += 65536) {
      const float* in; unsigned short* o8; int ci;
      if (i < 524288) { in = feat; o8 = Xb; ci = i; }
      else            { in = pw;   o8 = Wb; ci = i - 524288; }
      const float4* p = (const float4*)in + (size_t)ci * 2;
      float4 a = p[0], b = p[1];
      u16x8 o;
      o[0] = f32_to_bf16(a.x); o[1] = f32_to_bf16(a.y);
      o[2] = f32_to_bf16(a.z); o[3] = f32_to_bf16(a.w);
      o[4] = f32_to_bf16(b.x); o[5] = f32_to_bf16(b.y);
      o[6] = f32_to_bf16(b.z); o[7] = f32_to_bf16(b.w);
      *((u16x8*)o8 + ci) = o;
    }
  }
}

// ---- pipeline wait helper: N_TILE loads per K-tile, depth-2 prefetch ----
// after issuing at iter kt, tiles in flight beyond kt = min(2, ITERS-1-kt)
#define WAIT_VM(n)                                            \
  do {                                                        \
    if ((n) == 0) asm volatile("s_waitcnt vmcnt(0)" ::: "memory");   \
    else if ((n) == 1) asm volatile("s_waitcnt vmcnt(%0)" :: "i"(NT) : "memory"); \
    else asm volatile("s_waitcnt vmcnt(%0)" :: "i"(2 * NT) : "memory"); \
  } while (0)

// ---- 3-buffer, 2-deep-prefetch, counted-vmcnt 128x64-tile GEMM core ----
// 16 K-steps of 64. LDS: As 3x8192 elems (48 KB), Bs 3x4096 elems (24 KB).
// XOR-swizzled (colbyte ^= (row&7)<<4), pre-swizzled global source. NT=6 loads/tile.
__device__ __forceinline__ void gemm_core128(
    const unsigned short* __restrict__ Ap, const unsigned short* __restrict__ Btp,
    int arow0, int bcol0, int t,
    unsigned short* As, unsigned short* Bs, f32x4 (&acc)[4][2]) {
  constexpr int NT = 6;
  const int lane = t & 63;
  const int wid = t >> 6, wm = wid >> 1, wn = wid & 1;
  const int ar = t >> 3;
  const int acb = (((t & 7) ^ ((t >> 3) & 7)) << 4);
  const unsigned short* Abase = Ap + (size_t)(arow0 + ar) * FEAT + (acb >> 1);
  const unsigned short* Bbase = Btp + (size_t)(bcol0 + ar) * FEAT + (acb >> 1);
  unsigned short* AsP = As + t * 8;
  unsigned short* BsP = Bs + t * 8;

  // prologue: issue tiles 0,1 into buffers 0,1
#pragma unroll
  for (int kt = 0; kt < 2; ++kt) {
    const int ko = kt * 64;
#pragma unroll
    for (int p = 0; p < 4; ++p)
      gload_lds16(Abase + (size_t)(p * 32) * FEAT + ko, AsP + kt * 8192 + p * 2048);
#pragma unroll
    for (int p = 0; p < 2; ++p)
      gload_lds16(Bbase + (size_t)(p * 32) * FEAT + ko, BsP + kt * 4096 + p * 2048);
  }

  int o0 = 0, o1 = 1, o2 = 2;  // compute buf, next buf, prefetch-target buf
#pragma unroll
  for (int kt = 0; kt < 16; ++kt) {
    if (kt + 2 < 16) {
      const int ko = (kt + 2) * 64;
#pragma unroll
      for (int p = 0; p < 4; ++p)
        gload_lds16(Abase + (size_t)(p * 32) * FEAT + ko, AsP + o2 * 8192 + p * 2048);
#pragma unroll
      for (int p = 0; p < 2; ++p)
        gload_lds16(Bbase + (size_t)(p * 32) * FEAT + ko, BsP + o2 * 4096 + p * 2048);
      WAIT_VM(2);
    } else if (kt + 1 < 16) {
      WAIT_VM(1);
    } else {
      WAIT_VM(0);
    }
    __builtin_amdgcn_s_barrier();          // all waves' tile-kt data visible
    __builtin_amdgcn_sched_barrier(0);
    const char* Asc = (const char*)(As + o0 * 8192);
    const char* Bsc = (const char*)(Bs + o0 * 4096);
#pragma unroll
    for (int kk = 0; kk < 2; ++kk) {
      bf16x8 a[4], b[2];
      const int cbase = kk * 64 + ((lane >> 4) << 4);
#pragma unroll
      for (int m = 0; m < 4; ++m) {
        int r = wm * 64 + m * 16 + (lane & 15);
        a[m] = *(const bf16x8*)(Asc + r * 128 + (cbase ^ ((r & 7) << 4)));
      }
#pragma unroll
      for (int n = 0; n < 2; ++n) {
        int r = wn * 32 + n * 16 + (lane & 15);
        b[n] = *(const bf16x8*)(Bsc + r * 128 + (cbase ^ ((r & 7) << 4)));
      }
#pragma unroll
      for (int m = 0; m < 4; ++m)
#pragma unroll
        for (int n = 0; n < 2; ++n)
          acc[m][n] = __builtin_amdgcn_mfma_f32_16x16x32_bf16(a[m], b[n], acc[m][n], 0, 0, 0);
    }
    __builtin_amdgcn_s_barrier();          // reads of buf o0 done -> safe to overwrite next iter
    __builtin_amdgcn_sched_barrier(0);
    const int tmp = o0; o0 = o1; o1 = o2; o2 = tmp;
  }
}

// MODE 0 (L1, 512 blk): z=swz>>7; P1[z] = D2z + D2z+1 + D2z@D2z+1 -> O1+z*SM rows,
//        O2+(z>>1)*SM transposed if z odd.  lin = Dr.
// MODE 1 (L5, 512 blk): outf = A @ Bt^T (f32).
template <int MODE>
__global__ __launch_bounds__(256, 2) void gemm128(
    const unsigned short* __restrict__ A, const unsigned short* __restrict__ Bt,
    const unsigned short* __restrict__ lin,
    unsigned short* __restrict__ O1, unsigned short* __restrict__ O2,
    float* __restrict__ outf) {
  __shared__ __align__(16) unsigned short ldsbuf[36864];  // 72 KB: As 3x8192, Bs 3x4096
  unsigned short* As = ldsbuf;
  unsigned short* Bs = ldsbuf + 24576;

  const int t = threadIdx.x;
  const int lane = t & 63, wid = t >> 6, wm = wid >> 1, wn = wid & 1;
  const int swz = (blockIdx.x & 7) * 64 + (blockIdx.x >> 3);  // 512 blocks, XCD-bijective

  int bm, bn, z = 0;
  const unsigned short *Ap, *Btp;
  if (MODE == 0) {
    z = swz >> 7;
    const int rem = swz & 127;
    bm = rem >> 4; bn = rem & 15;
    Ap = A + (size_t)(2 * z) * SM;
    Btp = Bt + (size_t)z * SM;
  } else {
    bm = swz >> 4; bn = swz & 15;
    Ap = A; Btp = Bt;
  }

  f32x4 acc[4][2];
#pragma unroll
  for (int m = 0; m < 4; ++m)
#pragma unroll
    for (int n = 0; n < 2; ++n) acc[m][n] = (f32x4)0.f;

  gemm_core128(Ap, Btp, bm * 128, bn * 64, t, As, Bs, acc);

  // epilogue. C/D layout: col = lane&15, row = (lane>>4)*4 + reg [HW-verified]
#pragma unroll
  for (int m = 0; m < 4; ++m) {
    int Rb = bm * 128 + wm * 64 + m * 16 + ((lane >> 4) << 2);
#pragma unroll
    for (int n = 0; n < 2; ++n) {
      int C = bn * 64 + wn * 32 + n * 16 + (lane & 15);
      if (MODE == 0) {
        const unsigned short* aA = lin + (size_t)(2 * z) * SM;
        const unsigned short* aB = lin + (size_t)(2 * z + 1) * SM;
        unsigned short* pr = O1 + (size_t)z * SM;
        u16x4 tp;
#pragma unroll
        for (int r2 = 0; r2 < 4; ++r2) {
          size_t idx = (size_t)(Rb + r2) * FEAT + C;
          float v = acc[m][n][r2] + bf16_to_f32(aA[idx]) + bf16_to_f32(aB[idx]);
          unsigned short h = f32_to_bf16(v);
          pr[idx] = h; tp[r2] = h;
        }
        if (z & 1)
          *(u16x4*)(O2 + (size_t)(z >> 1) * SM + (size_t)C * FEAT + Rb) = tp;
      } else {
#pragma unroll
        for (int r2 = 0; r2 < 4; ++r2)
          outf[(size_t)(Rb + r2) * FEAT + C] = acc[m][n][r2];
      }
    }
  }
}

// ---- 64x64-tile full-K GEMM, 3-buffer pipeline (48 KB LDS), fused linear epilogue ----
// MODE 0 (L2, 512 blocks): z=swz>>8; P2[z] = P1_2z + P1_2z+1 + P1_2z@P1_2z+1
// MODE 1 (U/S, 256 blocks): O^T[C][k] = bf16( (A@Bt^T)[k][C] + lin[C][k] )
template <int MODE>
__global__ __launch_bounds__(256, 2) void gemm64(
    const unsigned short* __restrict__ A, const unsigned short* __restrict__ Bt,
    const unsigned short* __restrict__ lin, unsigned short* __restrict__ O) {
  constexpr int NT = 4;
  __shared__ __align__(16) unsigned short ldsbuf[24576];  // 48 KB: As 3x4096, Bs 3x4096
  unsigned short* As = ldsbuf;
  unsigned short* Bs = ldsbuf + 12288;

  const int t = threadIdx.x;
  const int lane = t & 63, wid = t >> 6, wm = wid >> 1, wn = wid & 1;
  const int nb = (int)gridDim.x;
  const int swz = (blockIdx.x & 7) * (nb >> 3) + (blockIdx.x >> 3);  // XCD-bijective

  int bm, bn, z = 0;
  const unsigned short *Ap, *Btp;
  if (MODE == 0) {
    z = swz >> 8;
    const int tile = swz & 255;
    bm = tile >> 4; bn = tile & 15;
    Ap = A + (size_t)(2 * z) * SM;
    Btp = Bt + (size_t)z * SM;
  } else {
    bm = swz >> 4; bn = swz & 15;
    Ap = A; Btp = Bt;
  }
  const int arow0 = bm * 64, bcol0 = bn * 64;

  f32x4 acc[2][2];
#pragma unroll
  for (int m = 0; m < 2; ++m)
#pragma unroll
    for (int n = 0; n < 2; ++n) acc[m][n] = (f32x4)0.f;

  const int ar = t >> 3;
  const int acb = (((t & 7) ^ ((t >> 3) & 7)) << 4);
  const unsigned short* Abase = Ap + (size_t)(arow0 + ar) * FEAT + (acb >> 1);
  const unsigned short* Bbase = Btp + (size_t)(bcol0 + ar) * FEAT + (acb >> 1);
  unsigned short* AsP = As + t * 8;
  unsigned short* BsP = Bs + t * 8;

  // prologue: tiles 0,1 -> buffers 0,1
#pragma unroll
  for (int kt = 0; kt < 2; ++kt) {
    const int ko = kt * 64;
#pragma unroll
    for (int p = 0; p < 2; ++p)
      gload_lds16(Abase + (size_t)(p * 32) * FEAT + ko, AsP + kt * 4096 + p * 2048);
#pragma unroll
    for (int p = 0; p < 2; ++p)
      gload_lds16(Bbase + (size_t)(p * 32) * FEAT + ko, BsP + kt * 4096 + p * 2048);
  }

  int o0 = 0, o1 = 1, o2 = 2;
#pragma unroll
  for (int kt = 0; kt < 16; ++kt) {
    if (kt + 2 < 16) {
      const int ko = (kt + 2) * 64;
#pragma unroll
      for (int p = 0; p < 2; ++p)
        gload_lds16(Abase + (size_t)(p * 32) * FEAT + ko, AsP + o2 * 4096 + p * 2048);
#pragma unroll
      for (int p = 0; p < 2; ++p)
        gload_lds16(Bbase + (size_t)(p * 32) * FEAT + ko, BsP + o2 * 4096 + p * 2048);
      WAIT_VM(2);
    } else if (kt + 1 < 16) {
      WAIT_VM(1);
    } else {
      WAIT_VM(0);
    }
    __builtin_amdgcn_s_barrier();
    __builtin_amdgcn_sched_barrier(0);
    const char* Asc = (const char*)(As + o0 * 4096);
    const char* Bsc = (const char*)(Bs + o0 * 4096);
#pragma unroll
    for (int kk = 0; kk < 2; ++kk) {
      bf16x8 a[2], b[2];
      const int cbase = kk * 64 + ((lane >> 4) << 4);
#pragma unroll
      for (int m = 0; m < 2; ++m) {
        int r = wm * 32 + m * 16 + (lane & 15);
        a[m] = *(const bf16x8*)(Asc + r * 128 + (cbase ^ ((r & 7) << 4)));
      }
#pragma unroll
      for (int n = 0; n < 2; ++n) {
        int r = wn * 32 + n * 16 + (lane & 15);
        b[n] = *(const bf16x8*)(Bsc + r * 128 + (cbase ^ ((r & 7) << 4)));
      }
#pragma unroll
      for (int m = 0; m < 2; ++m)
#pragma unroll
        for (int n = 0; n < 2; ++n)
          acc[m][n] = __builtin_amdgcn_mfma_f32_16x16x32_bf16(a[m], b[n], acc[m][n], 0, 0, 0);
    }
    __builtin_amdgcn_s_barrier();
    __builtin_amdgcn_sched_barrier(0);
    const int tmp = o0; o0 = o1; o1 = o2; o2 = tmp;
  }

  // epilogue
#pragma unroll
  for (int m = 0; m < 2; ++m) {
    int Rb = arow0 + wm * 32 + m * 16 + ((lane >> 4) << 2);
#pragma unroll
    for (int n = 0; n < 2; ++n) {
      int C = bcol0 + wn * 32 + n * 16 + (lane & 15);
      if (MODE == 0) {
        const unsigned short* aA = lin + (size_t)(2 * z) * SM;
        const unsigned short* aB = lin + (size_t)(2 * z + 1) * SM;
        unsigned short* po = O + (size_t)z * SM;
#pragma unroll
        for (int r2 = 0; r2 < 4; ++r2) {
          size_t idx = (size_t)(Rb + r2) * FEAT + C;
          float v = acc[m][n][r2] + bf16_to_f32(aA[idx]) + bf16_to_f32(aB[idx]);
          po[idx] = f32_to_bf16(v);
        }
      } else {
        u16x4 lv = *(const u16x4*)(lin + (size_t)C * FEAT + Rb);
        u16x4 o;
#pragma unroll
        for (int r2 = 0; r2 < 4; ++r2)
          o[r2] = f32_to_bf16(acc[m][n][r2] + bf16_to_f32(lv[r2]));
        *(u16x4*)(O + (size_t)C * FEAT + Rb) = o;  // transposed write
      }
    }
  }
}

extern "C" void kernel_launch(void* const* d_in, const int* in_sizes, int n_in,
                              void* d_out, int out_size, void* d_ws, size_t ws_size,
                              hipStream_t stream) {
  const float* features = (const float*)d_in[0];
  const float* eps      = (const float*)d_in[1];
  const float* mean     = (const float*)d_in[2];
  const float* logvar   = (const float*)d_in[3];
  const float* task_mats= (const float*)d_in[4];
  const float* proj_w   = (const float*)d_in[5];
  float* out = (float*)d_out;

  // workspace layout (peak 54 MB):
  uint8_t* ws = (uint8_t*)d_ws;
  unsigned short* Dr  = (unsigned short*)(ws);                      //  0..16M
  unsigned short* Dt  = (unsigned short*)(ws + ((size_t)16 << 20)); // 16..24M (odd-packed)
  unsigned short* Xb  = (unsigned short*)(ws + ((size_t)24 << 20)); // 24..32M
  unsigned short* Wb  = (unsigned short*)(ws + ((size_t)32 << 20)); // 32..34M
  unsigned short* P1r = (unsigned short*)(ws + ((size_t)34 << 20)); // 34..42M (4 slices)
  unsigned short* P1t = (unsigned short*)(ws + ((size_t)42 << 20)); // 42..46M (odd-packed)
  unsigned short* P2r = (unsigned short*)(ws + ((size_t)46 << 20)); // 46..50M (DL, DR rows)
  unsigned short* Ut  = (unsigned short*)(ws + ((size_t)50 << 20)); // 50..52M ((I+DR)W^T, transposed)
  unsigned short* St  = (unsigned short*)(ws + ((size_t)52 << 20)); // 52..54M (S, transposed)

  // prep: deltas + bf16 converts
  conv_all<<<2304, 256, 0, stream>>>(task_mats, features, proj_w, mean, eps, logvar,
                                     Dr, Dt, Xb, Wb);
  // L1: P1[z] = D2z + D2z+1 + D2z@D2z+1  (4 slices, 128x64 tiles, 512 blocks)
  gemm128<0><<<512, 256, 0, stream>>>(Dr, Dt, Dr, P1r, P1t, nullptr);
  // L2: P2[z] = P1_2z + P1_2z+1 + P1_2z@P1_2z+1  (2 slices, 64x64 tiles, 512 blocks)
  gemm64<0><<<512, 256, 0, stream>>>(P1r, P1t, P1r, P2r);
  // U = W^T + DR@W^T, written transposed: Ut[C][k]
  gemm64<1><<<256, 256, 0, stream>>>(P2r + SM, Wb, Wb, Ut);
  // S = U + DL@U, written transposed: St[C][k]
  gemm64<1><<<256, 256, 0, stream>>>(P2r, Ut, Ut, St);
  // L5: out = x @ S (f32, 128x64 tiles, 512 blocks)
  gemm128<1><<<512, 256, 0, stream>>>(Xb, St, nullptr, nullptr, nullptr, out);
}